// Round 7
// baseline (229.437 us; speedup 1.0000x reference)
//
#include <hip/hip_runtime.h>
#include <hip/hip_bf16.h>
#include <math.h>

#define B_  32
#define T_  128
#define NF_ 20
#define D_  512
#define S_  5
#define L_  96
#define EPS_ 1e-8f
#define NSEG (B_ * L_)                       // 3072
#define NPOS (NF_ - 1)                       // 19
#define NELEM (NF_ * D_)                     // 10240 floats = 40 KB
#define SPB 4                                // one segment per wave, 4 waves/block
#define NBLK (NSEG / SPB)                    // 768 blocks
#define GLD 21                               // Gram leading dim (20x21 fp32 per wave)

typedef short short8 __attribute__((ext_vector_type(8)));
typedef float f32x4  __attribute__((ext_vector_type(4)));

__device__ __forceinline__ unsigned f2bf2(float lo, float hi) {
  // round-to-nearest-even bf16, packed pair (lo in bits [15:0])
  unsigned ulo = __float_as_uint(lo);
  ulo += 0x7fffu + ((ulo >> 16) & 1u);
  unsigned uhi = __float_as_uint(hi);
  uhi += 0x7fffu + ((uhi >> 16) & 1u);
  return (uhi & 0xffff0000u) | (ulo >> 16);
}

__device__ __forceinline__ short8 pack8(float4 x, float4 y) {
  uint4 u;
  u.x = f2bf2(x.x, x.y); u.y = f2bf2(x.z, x.w);
  u.z = f2bf2(y.x, y.y); u.w = f2bf2(y.z, y.w);
  return __builtin_bit_cast(short8, u);
}

__global__ __launch_bounds__(256) void phoneme_ssl_seg_kernel(
    const float* __restrict__ out,
    const int* __restrict__ batch_idx,
    const int* __restrict__ time_idx,
    const int* __restrict__ neg_idx,
    float* __restrict__ partials) {

  __shared__ float G[SPB][NF_ * GLD];        // per-wave 20x21 Gram, ~6.7 KB total
  __shared__ float ws[SPB];

  const int wave = threadIdx.x >> 6;
  const int lane = threadIdx.x & 63;
  const int r = lane & 15;
  const int q = lane >> 4;                   // A/B k = q*8 + j

  // one segment per wave — fully independent load->MFMA stream
  const int n = blockIdx.x * SPB + wave;
  const float4* __restrict__ src4 =
      (const float4*)(out + (size_t)(batch_idx[n] * T_ + time_idx[n]) * NELEM);

  const int r1 = (16 + r > 19) ? 19 : 16 + r;   // clamp; cols >19 never stored
  const int o0 = r  * 128 + q * 2;              // float4 index: row r,  k-block q
  const int o1 = r1 * 128 + q * 2;

  f32x4 c00 = {0.f, 0.f, 0.f, 0.f}, c01 = c00, c11 = c00;

  // direct global->register->MFMA, 1-step software pipeline (no LDS staging)
  float4 A0a = src4[o0], A0b = src4[o0 + 1];
  float4 A1a = src4[o1], A1b = src4[o1 + 1];
#pragma unroll
  for (int ks = 0; ks < D_ / 32; ++ks) {
    float4 N0a, N0b, N1a, N1b;
    if (ks < 15) {
      const int oo = (ks + 1) * 8;
      N0a = src4[o0 + oo]; N0b = src4[o0 + oo + 1];
      N1a = src4[o1 + oo]; N1b = src4[o1 + oo + 1];
    }
    const short8 a0 = pack8(A0a, A0b);       // rows 0-15 fragment
    const short8 a1 = pack8(A1a, A1b);       // rows 16-19 fragment (clamped)
    // Gram: B-fragment == A-fragment; G symmetric -> only 3 tiles
    c00 = __builtin_amdgcn_mfma_f32_16x16x32_bf16(a0, a0, c00, 0, 0, 0);
    c01 = __builtin_amdgcn_mfma_f32_16x16x32_bf16(a0, a1, c01, 0, 0, 0);
    c11 = __builtin_amdgcn_mfma_f32_16x16x32_bf16(a1, a1, c11, 0, 0, 0);
    if (ks < 15) { A0a = N0a; A0b = N0b; A1a = N1a; A1b = N1b; }
  }

  // C/D layout (verified): col = lane&15, row = (lane>>4)*4 + reg
  {
    float* __restrict__ Gw = G[wave];
#pragma unroll
    for (int reg = 0; reg < 4; ++reg) {
      const int m = q * 4 + reg;
      Gw[m * GLD + r] = c00[reg];            // G[m][r], m,r in 0..15
      if (r < 4) {
        Gw[m * GLD + 16 + r]   = c01[reg];   // G[m][16+r]
        Gw[(16 + r) * GLD + m] = c01[reg];   // mirror: G[16+r][m] (symmetry)
        if (q == 0)
          Gw[(16 + reg) * GLD + 16 + r] = c11[reg];  // 4x4 diag block
      }
    }
  }
  __syncthreads();                           // waves are symmetric; arrive together

  // softmax rows: lanes 0..18 of EACH wave handle their own segment
  float local = 0.f;
  if (lane < NPOS) {
    const int i = lane;
    const float* __restrict__ Gc = G[wave];
    const float na = sqrtf(Gc[i * GLD + i]);
    float sims[1 + S_];
    {
      const float nb = sqrtf(Gc[(i + 1) * GLD + (i + 1)]);
      sims[0] = Gc[i * GLD + (i + 1)] / fmaxf(na * nb, EPS_);
    }
#pragma unroll
    for (int j = 0; j < S_; ++j) {
      const int f = neg_idx[i * S_ + j];
      const float nb = sqrtf(Gc[f * GLD + f]);
      sims[1 + j] = Gc[i * GLD + f] / fmaxf(na * nb, EPS_);
    }
    float m = sims[0];
#pragma unroll
    for (int j = 1; j < 1 + S_; ++j) m = fmaxf(m, sims[j]);
    float se = 0.f;
#pragma unroll
    for (int j = 0; j < 1 + S_; ++j) se += __expf(sims[j] - m);
    local = -(sims[0] - (m + __logf(se)));   // -log_softmax[...,0]
  }

  // per-wave reduce, then 4-way sum, one store per block
#pragma unroll
  for (int off = 32; off >= 1; off >>= 1)
    local += __shfl_xor(local, off, 64);
  if (lane == 0) ws[wave] = local;
  __syncthreads();
  if (threadIdx.x == 0)
    partials[blockIdx.x] = ws[0] + ws[1] + ws[2] + ws[3];
}

__global__ __launch_bounds__(256) void phoneme_ssl_reduce_kernel(
    const float* __restrict__ partials, float* __restrict__ loss_out) {
  float acc = 0.f;
  for (int i = threadIdx.x; i < NBLK; i += 256) acc += partials[i];
#pragma unroll
  for (int off = 32; off >= 1; off >>= 1)
    acc += __shfl_xor(acc, off, 64);
  __shared__ float ws[4];
  if ((threadIdx.x & 63) == 0) ws[threadIdx.x >> 6] = acc;
  __syncthreads();
  if (threadIdx.x == 0)
    loss_out[0] = (ws[0] + ws[1] + ws[2] + ws[3]) * (1.0f / (float)(NSEG * NPOS));
}

extern "C" void kernel_launch(void* const* d_in, const int* in_sizes, int n_in,
                              void* d_out, int out_size, void* d_ws, size_t ws_size,
                              hipStream_t stream) {
  const float* out_t    = (const float*)d_in[0];
  const int* batch_idx  = (const int*)d_in[1];
  const int* time_idx   = (const int*)d_in[2];
  const int* neg_idx    = (const int*)d_in[3];
  float* loss_out       = (float*)d_out;
  float* partials       = (float*)d_ws;      // NBLK floats, fully overwritten each call

  phoneme_ssl_seg_kernel<<<NBLK, 256, 0, stream>>>(
      out_t, batch_idx, time_idx, neg_idx, partials);
  phoneme_ssl_reduce_kernel<<<1, 256, 0, stream>>>(partials, loss_out);
}